// Round 3
// baseline (1002.858 us; speedup 1.0000x reference)
//
#include <hip/hip_runtime.h>
#include <stdint.h>

// Problem constants: B=2, S=2048, D=1024, H=16, DH=64
#define S_ 2048
#define NKT_ 32   // S_/64 key tiles
#define LP 72     // padded LDS row stride in shorts (144 B = 9*16 B, b128-aligned)

typedef short bf16x8 __attribute__((ext_vector_type(8)));
typedef float f32x4 __attribute__((ext_vector_type(4)));

// fp32 -> bf16 round-to-nearest-even
__device__ __forceinline__ short f2bf(float x) {
  union { float f; uint32_t u; } v; v.f = x;
  uint32_t r = v.u + 0x7fffu + ((v.u >> 16) & 1u);
  return (short)(r >> 16);
}
// bf16 bits -> fp32
__device__ __forceinline__ float bf2f(short s) {
  union { uint32_t u; float f; } v; v.u = ((uint32_t)(uint16_t)s) << 16;
  return v.f;
}

// Load 8 consecutive logical elements as bf16x8; dtype selected at runtime.
// isf32 is wave-uniform. Element offsets are multiples of 8 -> 16B/32B aligned.
__device__ __forceinline__ bf16x8 ld8(const void* base, long off, int isf32) {
  bf16x8 r;
  if (isf32) {
    const float* p = (const float*)base + off;
    f32x4 a = *(const f32x4*)p;
    f32x4 b = *(const f32x4*)(p + 4);
    r[0] = f2bf(a[0]); r[1] = f2bf(a[1]); r[2] = f2bf(a[2]); r[3] = f2bf(a[3]);
    r[4] = f2bf(b[0]); r[5] = f2bf(b[1]); r[6] = f2bf(b[2]); r[7] = f2bf(b[3]);
  } else {
    r = *(const bf16x8*)((const short*)base + off);
  }
  return r;
}

// ---------------------------------------------------------------------------
// dtype detector: bf16-pair words have exponent-structured bits[14:7];
// fp32 words have uniform mantissa bits there. Writes flag: 1 = fp32 tensors.
// ---------------------------------------------------------------------------
__global__ __launch_bounds__(256) void detect_dtype(const uint32_t* __restrict__ q,
                                                    uint32_t* __restrict__ flag) {
  __shared__ int cnt;
  int t = threadIdx.x;
  if (t == 0) cnt = 0;
  __syncthreads();
  uint32_t w = q[t];
  int e = (int)((w >> 7) & 0xFF);             // exponent field of low-half bf16
  int hit = (e >= 100 && e <= 141) ? 1 : 0;   // bf16 data: ~256/256; fp32: ~42/256
  atomicAdd(&cnt, hit);
  __syncthreads();
  if (t == 0) *flag = (cnt >= 200) ? 0u : 1u;
}

// ---------------------------------------------------------------------------
// NT GEMM: C[m,n] = sum_k A[m,k]*W[n,k], M=4096, N=K=1024, tile 128x128xBK64.
// MODE 0: dst=qh [b,h,s,dh] bf16, scaled by 0.125*log2(e)
// MODE 1: dst=kh [b,h,s,dh] bf16
// MODE 2: dst=vt [b,h,dh,s] bf16 (A/B roles swapped so D is transposed)
// MODE 3: dst=out row-major [m,n]; fp32 (dstF) when outf, else bf16 (dst)
// ---------------------------------------------------------------------------
template <int MODE>
__device__ __forceinline__ void gemm_body(short* sA, short* sW,
    const void* A, const void* W, int fA, int fW,
    short* __restrict__ dst, float* __restrict__ dstF, int outf) {
  const int tid = threadIdx.x;
  const int wave = tid >> 6, lane = tid & 63;
  const int quad = lane >> 4, l16 = lane & 15;
  const int m0 = blockIdx.x * 128, n0 = blockIdx.y * 128;
  const int wm = wave >> 1, wn = wave & 1;

  f32x4 acc[4][4] = {};

  for (int k0 = 0; k0 < 1024; k0 += 64) {
    // stage 128x64 A-tile and W-tile, register-mediated, padded LDS
    for (int c = tid; c < 1024; c += 256) {
      int r = c >> 3, ch = c & 7;
      *(bf16x8*)(sA + r * LP + ch * 8) = ld8(A, (long)(m0 + r) * 1024 + k0 + ch * 8, fA);
      *(bf16x8*)(sW + r * LP + ch * 8) = ld8(W, (long)(n0 + r) * 1024 + k0 + ch * 8, fW);
    }
    __syncthreads();  // staged tiles visible
    const short* Pa = (MODE == 2) ? sW : sA;  // A-operand source
    const short* Pb = (MODE == 2) ? sA : sW;  // B-operand source
#pragma unroll
    for (int kk = 0; kk < 2; ++kk) {
      bf16x8 af[4], bfr[4];
#pragma unroll
      for (int i = 0; i < 4; ++i)
        af[i] = *(const bf16x8*)(Pa + (wm * 64 + i * 16 + l16) * LP + (kk * 4 + quad) * 8);
#pragma unroll
      for (int j = 0; j < 4; ++j)
        bfr[j] = *(const bf16x8*)(Pb + (wn * 64 + j * 16 + l16) * LP + (kk * 4 + quad) * 8);
#pragma unroll
      for (int i = 0; i < 4; ++i)
#pragma unroll
        for (int j = 0; j < 4; ++j)
          acc[i][j] = __builtin_amdgcn_mfma_f32_16x16x32_bf16(af[i], bfr[j], acc[i][j], 0, 0, 0);
    }
    __syncthreads();  // all frag reads done before restage
  }

  // Epilogue. C/D layout: col = lane&15, row = quad*4 + reg (m89-verified).
#pragma unroll
  for (int i = 0; i < 4; ++i)
#pragma unroll
    for (int j = 0; j < 4; ++j)
#pragma unroll
      for (int r = 0; r < 4; ++r) {
        float vv = acc[i][j][r];
        if (MODE == 0) vv *= 0.18033688011112042f;  // 0.125 * log2(e)
        if (MODE == 2) {
          int n = n0 + wm * 64 + i * 16 + quad * 4 + r;  // W row = channel
          int m = m0 + wn * 64 + j * 16 + l16;           // A row = token
          int b = m >> 11, s = m & 2047, h = n >> 6, dh = n & 63;
          dst[((long)((b * 16 + h) * 64 + dh)) * 2048 + s] = f2bf(vv);
        } else {
          int m = m0 + wm * 64 + i * 16 + quad * 4 + r;
          int n = n0 + wn * 64 + j * 16 + l16;
          if (MODE == 3) {
            if (outf) dstF[(long)m * 1024 + n] = vv;
            else      dst[(long)m * 1024 + n] = f2bf(vv);
          } else {
            int b = m >> 11, s = m & 2047, h = n >> 6, dh = n & 63;
            dst[((long)(b * 16 + h) * 2048 + s) * 64 + dh] = f2bf(vv);
          }
        }
      }
}

__global__ __launch_bounds__(256) void qkv_kernel(
    const void* __restrict__ q, const void* __restrict__ k, const void* __restrict__ v,
    const void* __restrict__ Wq, const void* __restrict__ Wk, const void* __restrict__ Wv,
    const uint32_t* __restrict__ flag,
    short* __restrict__ qh, short* __restrict__ kh, short* __restrict__ vt) {
  __shared__ __align__(16) short sA[128 * LP];
  __shared__ __align__(16) short sW[128 * LP];
  const int f = (int)*flag;
  if (blockIdx.z == 0)      gemm_body<0>(sA, sW, q, Wq, f, f, qh, nullptr, 0);
  else if (blockIdx.z == 1) gemm_body<1>(sA, sW, k, Wk, f, f, kh, nullptr, 0);
  else                      gemm_body<2>(sA, sW, v, Wv, f, f, vt, nullptr, 0);
}

__global__ __launch_bounds__(256) void oproj_kernel(
    const short* __restrict__ o, const void* __restrict__ Wo,
    const uint32_t* __restrict__ flag,
    short* __restrict__ outB, float* __restrict__ outF) {
  __shared__ __align__(16) short sA[128 * LP];
  __shared__ __align__(16) short sW[128 * LP];
  const int f = (int)*flag;
  gemm_body<3>(sA, sW, (const void*)o, Wo, 0, f, outB, outF, f);
}

// ---------------------------------------------------------------------------
// Pack attn_mask (S x S int32, 0/1) into bits: word q*64 + (k>>5), bit k&31.
// ---------------------------------------------------------------------------
__global__ __launch_bounds__(256) void pack_mask(const int* __restrict__ mask,
                                                 uint32_t* __restrict__ bits) {
  int gt = blockIdx.x * 256 + threadIdx.x;
  int wid = gt >> 6, lane = gt & 63;
  int nw = (gridDim.x * 256) >> 6;
  for (int g = wid; g < (S_ * S_) / 64; g += nw) {
    int v = mask[(long)g * 64 + lane];
    unsigned long long b = __ballot(v != 0);
    if (lane == 0) bits[2 * g] = (uint32_t)b;
    if (lane == 1) bits[2 * g + 1] = (uint32_t)(b >> 32);
  }
}

// ---------------------------------------------------------------------------
// Attention: per (bh, 128-q tile): two passes over 64-key tiles.
// qh pre-scaled by 0.125*log2(e) -> softmax via exp2 (v_exp_f32) directly.
// Internal tensors (qh, kh, vt, o) are bf16; attn written fp32 when outf.
// ---------------------------------------------------------------------------
__global__ __launch_bounds__(256) void attn_kernel(
    const short* __restrict__ qh, const short* __restrict__ kh,
    const short* __restrict__ vt, const uint32_t* __restrict__ mbits,
    const uint32_t* __restrict__ flag,
    short* __restrict__ attnB, float* __restrict__ attnF, short* __restrict__ o) {
  __shared__ __align__(16) short sK[64 * LP];
  __shared__ __align__(16) short sV[64 * LP];
  __shared__ __align__(16) short sP[4][32 * LP];  // per-wave P tile
  const int tid = threadIdx.x;
  const int wave = tid >> 6, lane = tid & 63;
  const int quad = lane >> 4, l16 = lane & 15;
  const int q0 = blockIdx.x * 128;
  const int bh = blockIdx.y;
  const int outf = (int)*flag;
  const short* Qb = qh + (long)bh * S_ * 64;
  const short* Kb = kh + (long)bh * S_ * 64;
  const short* Vb = vt + (long)bh * 64 * S_;
  short* attnBb = attnB + (long)bh * S_ * S_;
  float* attnFb = attnF + (long)bh * S_ * S_;
  short* sPw = sP[wave];
  const uint32_t cm0 = 1u << l16, cm1 = 1u << (l16 + 16);

  // Q fragments, loop-invariant, straight from global (16B/lane, aligned)
  bf16x8 qf[2][2];
#pragma unroll
  for (int i = 0; i < 2; ++i)
#pragma unroll
    for (int kk = 0; kk < 2; ++kk)
      qf[i][kk] = *(const bf16x8*)(Qb + (long)(q0 + wave * 32 + i * 16 + l16) * 64 + kk * 32 + quad * 8);

  float mrun[2][4], lrun[2][4];
#pragma unroll
  for (int i = 0; i < 2; ++i)
#pragma unroll
    for (int r = 0; r < 4; ++r) { mrun[i][r] = -3e38f; lrun[i][r] = 0.f; }

  // ---------------- pass A: row max + sum ----------------
  for (int kt = 0; kt < NKT_; ++kt) {
    const int k0 = kt * 64;
    for (int c = tid; c < 512; c += 256) {       // stage K tile (64 keys x 64 dh)
      int r = c >> 3, ch = c & 7;
      *(bf16x8*)(sK + r * LP + ch * 8) = *(const bf16x8*)(Kb + (long)(k0 + r) * 64 + ch * 8);
    }
    __syncthreads();
    f32x4 acc[2][4] = {};
#pragma unroll
    for (int kk = 0; kk < 2; ++kk) {
      bf16x8 bfr[4];
#pragma unroll
      for (int j = 0; j < 4; ++j)
        bfr[j] = *(const bf16x8*)(sK + (j * 16 + l16) * LP + (kk * 4 + quad) * 8);
#pragma unroll
      for (int i = 0; i < 2; ++i)
#pragma unroll
        for (int j = 0; j < 4; ++j)
          acc[i][j] = __builtin_amdgcn_mfma_f32_16x16x32_bf16(qf[i][kk], bfr[j], acc[i][j], 0, 0, 0);
    }
#pragma unroll
    for (int i = 0; i < 2; ++i)
#pragma unroll
      for (int r = 0; r < 4; ++r) {
        int qrow = q0 + wave * 32 + i * 16 + quad * 4 + r;
        const uint32_t* wp = mbits + qrow * 64 + (k0 >> 5);
        uint32_t w0 = wp[0], w1 = wp[1];
        float s0 = (w0 & cm0) ? acc[i][0][r] : -1e30f;
        float s1 = (w0 & cm1) ? acc[i][1][r] : -1e30f;
        float s2 = (w1 & cm0) ? acc[i][2][r] : -1e30f;
        float s3 = (w1 & cm1) ? acc[i][3][r] : -1e30f;
        float mx = fmaxf(fmaxf(s0, s1), fmaxf(s2, s3));
        mx = fmaxf(mx, __shfl_xor(mx, 1));
        mx = fmaxf(mx, __shfl_xor(mx, 2));
        mx = fmaxf(mx, __shfl_xor(mx, 4));
        mx = fmaxf(mx, __shfl_xor(mx, 8));
        float mold = mrun[i][r];
        float mnew = fmaxf(mold, mx);
        float sum = exp2f(s0 - mnew) + exp2f(s1 - mnew) + exp2f(s2 - mnew) + exp2f(s3 - mnew);
        sum += __shfl_xor(sum, 1);
        sum += __shfl_xor(sum, 2);
        sum += __shfl_xor(sum, 4);
        sum += __shfl_xor(sum, 8);
        lrun[i][r] = lrun[i][r] * exp2f(mold - mnew) + sum;
        mrun[i][r] = mnew;
      }
    __syncthreads();  // all sK reads done before restage
  }

  float invl[2][4];
#pragma unroll
  for (int i = 0; i < 2; ++i)
#pragma unroll
    for (int r = 0; r < 4; ++r) invl[i][r] = 1.0f / lrun[i][r];

  f32x4 acco[2][4] = {};

  // ---------------- pass B: p, attn write, PV ----------------
  for (int kt = 0; kt < NKT_; ++kt) {
    const int k0 = kt * 64;
    for (int c = tid; c < 512; c += 256) {       // stage K and V^T tiles
      int r = c >> 3, ch = c & 7;
      *(bf16x8*)(sK + r * LP + ch * 8) = *(const bf16x8*)(Kb + (long)(k0 + r) * 64 + ch * 8);
      *(bf16x8*)(sV + r * LP + ch * 8) = *(const bf16x8*)(Vb + (long)r * S_ + k0 + ch * 8);
    }
    __syncthreads();
    f32x4 acc[2][4] = {};
#pragma unroll
    for (int kk = 0; kk < 2; ++kk) {
      bf16x8 bfr[4];
#pragma unroll
      for (int j = 0; j < 4; ++j)
        bfr[j] = *(const bf16x8*)(sK + (j * 16 + l16) * LP + (kk * 4 + quad) * 8);
#pragma unroll
      for (int i = 0; i < 2; ++i)
#pragma unroll
        for (int j = 0; j < 4; ++j)
          acc[i][j] = __builtin_amdgcn_mfma_f32_16x16x32_bf16(qf[i][kk], bfr[j], acc[i][j], 0, 0, 0);
    }
    // write normalized P into per-wave padded LDS tile (plain layout, row*LP+col)
#pragma unroll
    for (int i = 0; i < 2; ++i)
#pragma unroll
      for (int r = 0; r < 4; ++r) {
        int qrow = q0 + wave * 32 + i * 16 + quad * 4 + r;
        const uint32_t* wp = mbits + qrow * 64 + (k0 >> 5);
        uint32_t w0 = wp[0], w1 = wp[1];
        float mm = mrun[i][r], il = invl[i][r];
        float s0 = (w0 & cm0) ? acc[i][0][r] : -1e30f;
        float s1 = (w0 & cm1) ? acc[i][1][r] : -1e30f;
        float s2 = (w1 & cm0) ? acc[i][2][r] : -1e30f;
        float s3 = (w1 & cm1) ? acc[i][3][r] : -1e30f;
        int rowL = i * 16 + quad * 4 + r;
        short* rp = sPw + rowL * LP;
        rp[0  + l16] = f2bf(exp2f(s0 - mm) * il);
        rp[16 + l16] = f2bf(exp2f(s1 - mm) * il);
        rp[32 + l16] = f2bf(exp2f(s2 - mm) * il);
        rp[48 + l16] = f2bf(exp2f(s3 - mm) * il);
      }
    __syncthreads();  // P writes visible (also compiler barrier)
    // PV: A = P (from own sPw), B = V^T rows
    bf16x8 vf[2][4];
#pragma unroll
    for (int kk = 0; kk < 2; ++kk)
#pragma unroll
      for (int jd = 0; jd < 4; ++jd)
        vf[kk][jd] = *(const bf16x8*)(sV + (jd * 16 + l16) * LP + (kk * 4 + quad) * 8);
#pragma unroll
    for (int kk = 0; kk < 2; ++kk)
#pragma unroll
      for (int i = 0; i < 2; ++i) {
        bf16x8 pf = *(const bf16x8*)(sPw + (i * 16 + l16) * LP + (kk * 4 + quad) * 8);
#pragma unroll
        for (int jd = 0; jd < 4; ++jd)
          acco[i][jd] = __builtin_amdgcn_mfma_f32_16x16x32_bf16(pf, vf[kk][jd], acco[i][jd], 0, 0, 0);
      }
    // attn tile out: read P rows from LDS, store fp32 (32B/lane) or bf16 (16B/lane)
#pragma unroll
    for (int it = 0; it < 4; ++it) {
      int cid = it * 64 + lane;
      int rowL = cid >> 3, kc = cid & 7;
      bf16x8 vals = *(const bf16x8*)(sPw + rowL * LP + kc * 8);
      long base = (long)(q0 + wave * 32 + rowL) * S_ + k0 + kc * 8;
      if (outf) {
        f32x4 lo, hi;
#pragma unroll
        for (int e = 0; e < 4; ++e) { lo[e] = bf2f(vals[e]); hi[e] = bf2f(vals[e + 4]); }
        *(f32x4*)(attnFb + base) = lo;
        *(f32x4*)(attnFb + base + 4) = hi;
      } else {
        *(bf16x8*)(attnBb + base) = vals;
      }
    }
    __syncthreads();  // all sK/sV/sP reads done before restage
  }

  // o epilogue: [b, s, h*64+dh], internal bf16
  const int b = bh >> 4, h = bh & 15;
#pragma unroll
  for (int i = 0; i < 2; ++i)
#pragma unroll
    for (int jd = 0; jd < 4; ++jd)
#pragma unroll
      for (int r = 0; r < 4; ++r) {
        int qrow = q0 + wave * 32 + i * 16 + quad * 4 + r;
        int dh = jd * 16 + l16;
        o[(long)(b * S_ + qrow) * 1024 + h * 64 + dh] = f2bf(acco[i][jd][r]);
      }
}

extern "C" void kernel_launch(void* const* d_in, const int* in_sizes, int n_in,
                              void* d_out, int out_size, void* d_ws, size_t ws_size,
                              hipStream_t stream) {
  (void)in_sizes; (void)n_in; (void)out_size; (void)ws_size;
  const void* q  = d_in[0];
  const void* k  = d_in[1];
  const void* v  = d_in[2];
  const int* mask = (const int*)d_in[3];
  const void* Wq = d_in[4];
  const void* Wk = d_in[5];
  const void* Wv = d_in[6];
  const void* Wo = d_in[7];

  // d_out = out [2,2048,1024] then attn [2,16,2048,2048], dtype per flag
  short* outB  = (short*)d_out;
  short* attnB = outB + (long)4194304;
  float* outF  = (float*)d_out;
  float* attnF = outF + (long)4194304;

  short* qh = (short*)d_ws;            // [2,16,2048,64] bf16, pre-scaled
  short* kh = qh + (long)4194304;      // [2,16,2048,64] bf16
  short* vt = kh + (long)4194304;      // [2,16,64,2048] bf16
  short* o  = vt + (long)4194304;      // [2,2048,1024] bf16
  uint32_t* mbits = (uint32_t*)(o + (long)4194304);  // [2048][64] words
  uint32_t* flag  = mbits + 131072;    // 1 = fp32 tensors

  detect_dtype<<<dim3(1), dim3(256), 0, stream>>>((const uint32_t*)q, flag);
  pack_mask<<<dim3(256), dim3(256), 0, stream>>>(mask, mbits);
  qkv_kernel<<<dim3(32, 8, 3), dim3(256), 0, stream>>>(q, k, v, Wq, Wk, Wv, flag, qh, kh, vt);
  attn_kernel<<<dim3(16, 32), dim3(256), 0, stream>>>(qh, kh, vt, mbits, flag, attnB, attnF, o);
  oproj_kernel<<<dim3(32, 8), dim3(256), 0, stream>>>(o, Wo, flag, outB, outF);
}